// Round 12
// baseline (1494.942 us; speedup 1.0000x reference)
//
#include <hip/hip_runtime.h>

// ---------------------------------------------------------------------------
// Child-Sum TreeLSTM, complete binary tree, level-wise bottom-up, bf16 MFMA.
// Round 12: R11 proved weights-in-LDS doesn't move the 383us plateau ->
// the cost is A-fragment load latency, serialized (~500cy/load, 224/tile).
// Fix: (a) child epilogue writes hsum / h-even / packed-c-pair buffers
// (sibling rows are in-lane adjacent in the 16x16 D-layout) -> parent
// A-loads are coalesced 512B-stride and 3x fewer (iou reads hsum once;
// f2 = xf + hsum@Wfh - h1@Wfh needs no h2; c1|c2 one 4B load);
// (b) mfma 16x16x32: small acc planes -> x A-frags held in 32 regs for the
// whole tile, a1/ahs issued as 8-deep batches -> ~12 loads in flight;
// (c) weights stay LDS-resident (R11), 8 cg-blocks/stripe share an XCD.
//
// mfma_f32_16x16x32_bf16: A lane: row=l&15, k=(l>>4)*8+e  (16B/lane)
//                         B lane: col=l&15, k=(l>>4)*8+e = W[col][k]
//                         D: col=l&15, row=(l>>4)*4+r, r=0..3
// ---------------------------------------------------------------------------

typedef __attribute__((ext_vector_type(8))) short bf16x8;
typedef __attribute__((ext_vector_type(8))) unsigned short us8;
typedef __attribute__((ext_vector_type(4))) float f32x4;
typedef __attribute__((ext_vector_type(4))) float f4;

#define MFMA16(A, B, C) __builtin_amdgcn_mfma_f32_16x16x32_bf16(A, B, C, 0, 0, 0)

__device__ __forceinline__ unsigned short f2b(float f) {
  unsigned int u = __builtin_bit_cast(unsigned int, f);
  u = u + 0x7FFFu + ((u >> 16) & 1u);   // RNE
  return (unsigned short)(u >> 16);
}
__device__ __forceinline__ float bf2f(unsigned short u) {
  unsigned int v = (unsigned int)u << 16;
  return __builtin_bit_cast(float, v);
}
__device__ __forceinline__ us8 pack8(f4 a, f4 b) {
  us8 r;
  r[0] = f2b(a[0]); r[1] = f2b(a[1]); r[2] = f2b(a[2]); r[3] = f2b(a[3]);
  r[4] = f2b(b[0]); r[5] = f2b(b[1]); r[6] = f2b(b[2]); r[7] = f2b(b[3]);
  return r;
}
__device__ __forceinline__ float sigm(float x) { return 1.0f / (1.0f + __expf(-x)); }
__device__ __forceinline__ float tanh_f(float x) { return 2.0f / (1.0f + __expf(-2.0f * x)) - 1.0f; }

__global__ void pack_w(const float* __restrict__ a,  // Wioux 768x256
                       const float* __restrict__ b,  // Wiouh 768x256
                       const float* __restrict__ c,  // Wfx   256x256
                       const float* __restrict__ d,  // Wfh   256x256
                       unsigned short* __restrict__ out) {
  int i = blockIdx.x * blockDim.x + threadIdx.x;  // 0 .. 524287
  const int A = 768 * 256;
  const int B = A + 768 * 256;
  const int C = B + 256 * 256;
  float v;
  if (i < A)      v = a[i];
  else if (i < B) v = b[i - A];
  else if (i < C) v = c[i - B];
  else            v = d[i - C];
  out[i] = f2b(v);
}

// convert ALL node x rows to bf16 (8 elems/thread)
__global__ void conv_x(const float* __restrict__ x, unsigned short* __restrict__ xb, int n8) {
  int i = blockIdx.x * blockDim.x + threadIdx.x;
  if (i >= n8) return;
  f4 a = __builtin_nontemporal_load((const f4*)(x + (size_t)i * 8));
  f4 b = __builtin_nontemporal_load((const f4*)(x + (size_t)i * 8 + 4));
  __builtin_nontemporal_store(pack8(a, b), (us8*)(xb + (size_t)i * 8));
}

// LDS weight planes: 0 Wx_i, 1 Wx_o, 2 Wx_u, 3 Wh_i, 4 Wh_o, 5 Wh_u, 6 Wfx, 7 Wfh
// layout per plane: [kc8][kg4][col32][e8]  (frag-ordered, conflict-free b128)
template<int LEAF>
__global__ __launch_bounds__(512, 2) void level_k(
    const unsigned short* __restrict__ xb,     // [N][256] bf16
    const unsigned short* __restrict__ wb,     // packed bf16 weights
    const float* __restrict__ bioux,
    const float* __restrict__ bfx,
    const float* __restrict__ fb,
    float* __restrict__ h_all,                 // d_out + 512
    const unsigned short* __restrict__ hs_r,   // hsum of children, parent-local
    const unsigned short* __restrict__ hbe_r,  // h of even child, parent-local
    const unsigned int* __restrict__ cp_r,     // packed (c1|c2), parent-local
    unsigned short* __restrict__ hs_w,         // same, for level d-1
    unsigned short* __restrict__ hbe_w,
    unsigned int* __restrict__ cp_w,
    float* __restrict__ out0,
    int s, int L, int T64, int root)
{
  extern __shared__ unsigned short W[];

  const int tid    = threadIdx.x;
  const int cg     = blockIdx.x >> 5;    // 0..7 column group (32 cols)
  const int stripe = blockIdx.x & 31;    // XCD = blockIdx.x % 8 = stripe % 8

  // ---- stage weights for this cg into LDS (once) ----
  const int NP = LEAF ? 3 : 8;
  #pragma unroll 1
  for (int c = tid; c < NP * 1024; c += 512) {
    const int p  = c >> 10;
    const int q  = c & 1023;
    const int col = q & 31;
    const int kg  = (q >> 5) & 3;
    const int kc  = q >> 7;
    const int po = (p < 3) ? p * 65536
                 : (p < 6) ? 196608 + (p - 3) * 65536
                 : (p == 6) ? 393216 : 458752;
    us8 v = *(const us8*)(wb + po + (size_t)(cg * 32 + col) * 256 + kc * 32 + kg * 8);
    *(us8*)(W + p * 8192 + ((kc * 4 + kg) * 32 + col) * 8) = v;
  }
  __syncthreads();   // only barrier; waves free-run after

  const int lane = tid & 63;
  const int wv   = tid >> 6;          // 0..7
  const int sub  = wv >> 1;           // node subtile 0..3
  const int ch   = wv & 1;            // col half 0..1
  const int lm   = lane & 15;
  const int kgl  = lane >> 4;         // 0..3
  const int colc = cg * 32 + ch * 16 + lm;

  const unsigned short* LW = W + (size_t)(kgl * 32 + ch * 16 + lm) * 8;  // +p*8192 +kc*1024

  const float bi_ = bioux[colc];
  const float bo_ = bioux[256 + colc];
  const float bu_ = bioux[512 + colc];
  const float bf_ = LEAF ? 0.f : (bfx[colc] + fb[colc]);

  const int Tper = (T64 + 31) >> 5;
  const int t0   = stripe * Tper;
  const int tE   = (t0 + Tper < T64) ? (t0 + Tper) : T64;

  for (int t = t0; t < tE; ++t) {
    const int tb16  = t * 64 + sub * 16;          // level-local first row of subtile
    const int drow0 = tb16 + kgl * 4;             // D-layout row base (multiple of 4)
    const unsigned short* xr = xb + (size_t)(s + tb16 + lm) * 256 + kgl * 8;

    const f32x4 z4 = {0.f, 0.f, 0.f, 0.f};

    // x A-frags: loaded once, used by both passes (32 VGPR)
    bf16x8 ax[8];
    #pragma unroll
    for (int kc = 0; kc < 8; ++kc) ax[kc] = *(const bf16x8*)(xr + kc * 32);

    if (!LEAF) {
      const unsigned short* hbr = hbe_r + (size_t)(tb16 + lm) * 256 + kgl * 8;
      const unsigned short* hsr = hs_r  + (size_t)(tb16 + lm) * 256 + kgl * 8;

      // h1 A-frags batch (in flight with ax)
      bf16x8 a1[8];
      #pragma unroll
      for (int kc = 0; kc < 8; ++kc) a1[kc] = *(const bf16x8*)(hbr + kc * 32);

      // children c (one packed 4B per D-row; latency hidden under both passes)
      unsigned int cpv[4];
      #pragma unroll
      for (int r = 0; r < 4; ++r)
        cpv[r] = cp_r[(size_t)(drow0 + r) * 256 + colc];

      // ---- pass F: xf = x@Wfx (p6), f1h = h1@Wfh (p7) ----
      f32x4 xf = z4, f1h = z4;
      #pragma unroll
      for (int kc = 0; kc < 8; ++kc) {
        bf16x8 b6 = *(const bf16x8*)(LW + 6 * 8192 + kc * 1024);
        bf16x8 b7 = *(const bf16x8*)(LW + 7 * 8192 + kc * 1024);
        xf  = MFMA16(ax[kc], b6, xf);
        f1h = MFMA16(a1[kc], b7, f1h);
      }

      // hsum A-frags (issued while pass F tail drains; land during IOU)
      bf16x8 ahs[8];
      #pragma unroll
      for (int kc = 0; kc < 8; ++kc) ahs[kc] = *(const bf16x8*)(hsr + kc * 32);

      // ---- pass IOU + fs: i,o,u = x@Wx + hsum@Wh ; fs = hsum@Wfh ----
      f32x4 ai = z4, ao = z4, au = z4, fs = z4;
      #pragma unroll
      for (int kc = 0; kc < 8; ++kc) {
        bf16x8 b0 = *(const bf16x8*)(LW + 0 * 8192 + kc * 1024);
        bf16x8 b1 = *(const bf16x8*)(LW + 1 * 8192 + kc * 1024);
        bf16x8 b2 = *(const bf16x8*)(LW + 2 * 8192 + kc * 1024);
        bf16x8 b3 = *(const bf16x8*)(LW + 3 * 8192 + kc * 1024);
        bf16x8 b4 = *(const bf16x8*)(LW + 4 * 8192 + kc * 1024);
        bf16x8 b5 = *(const bf16x8*)(LW + 5 * 8192 + kc * 1024);
        bf16x8 b7 = *(const bf16x8*)(LW + 7 * 8192 + kc * 1024);
        ai = MFMA16(ax[kc],  b0, ai);
        ao = MFMA16(ax[kc],  b1, ao);
        au = MFMA16(ax[kc],  b2, au);
        ai = MFMA16(ahs[kc], b3, ai);
        ao = MFMA16(ahs[kc], b4, ao);
        au = MFMA16(ahs[kc], b5, au);
        fs = MFMA16(ahs[kc], b7, fs);
      }

      // ---- epilogue ----
      float hv4[4], cv4[4];
      #pragma unroll
      for (int r = 0; r < 4; ++r) {
        const float i_ = sigm(ai[r] + bi_);
        const float u_ = tanh_f(au[r] + bu_);
        const float o_ = sigm(ao[r] + bo_);
        const float f1 = sigm(xf[r] + f1h[r] + bf_);
        const float f2 = sigm(xf[r] + fs[r] - f1h[r] + bf_);  // h2@W = hs@W - h1@W
        const float c1 = bf2f((unsigned short)(cpv[r] & 0xffffu));
        const float c2 = bf2f((unsigned short)(cpv[r] >> 16));
        const float c_ = i_ * u_ + f1 * c1 + f2 * c2;
        const float h_ = o_ * tanh_f(c_);
        cv4[r] = c_; hv4[r] = h_;
        const int j = drow0 + r;
        if (j < L)
          __builtin_nontemporal_store(h_, h_all + (size_t)(s + j) * 256 + colc);
      }
      if (root) {
        if (drow0 == 0) { out0[colc] = hv4[0]; out0[256 + colc] = cv4[0]; }
      } else {
        #pragma unroll
        for (int rp = 0; rp < 2; ++rp) {
          const int j0 = drow0 + rp * 2;
          if (j0 + 1 < L) {
            const int p = j0 >> 1;
            hs_w [(size_t)p * 256 + colc] = f2b(hv4[rp*2] + hv4[rp*2+1]);
            hbe_w[(size_t)p * 256 + colc] = f2b(hv4[rp*2]);
            cp_w [(size_t)p * 256 + colc] =
                (unsigned int)f2b(cv4[rp*2]) | ((unsigned int)f2b(cv4[rp*2+1]) << 16);
          }
        }
      }
    } else {
      // ---- leaf: i,o,u from x only ----
      f32x4 ai = z4, ao = z4, au = z4;
      #pragma unroll
      for (int kc = 0; kc < 8; ++kc) {
        bf16x8 b0 = *(const bf16x8*)(LW + 0 * 8192 + kc * 1024);
        bf16x8 b1 = *(const bf16x8*)(LW + 1 * 8192 + kc * 1024);
        bf16x8 b2 = *(const bf16x8*)(LW + 2 * 8192 + kc * 1024);
        ai = MFMA16(ax[kc], b0, ai);
        ao = MFMA16(ax[kc], b1, ao);
        au = MFMA16(ax[kc], b2, au);
      }
      float hv4[4], cv4[4];
      #pragma unroll
      for (int r = 0; r < 4; ++r) {
        const float i_ = sigm(ai[r] + bi_);
        const float u_ = tanh_f(au[r] + bu_);
        const float o_ = sigm(ao[r] + bo_);
        const float c_ = i_ * u_;
        const float h_ = o_ * tanh_f(c_);
        cv4[r] = c_; hv4[r] = h_;
        __builtin_nontemporal_store(h_, h_all + (size_t)(s + drow0 + r) * 256 + colc);
      }
      #pragma unroll
      for (int rp = 0; rp < 2; ++rp) {
        const int p = (drow0 + rp * 2) >> 1;
        hs_w [(size_t)p * 256 + colc] = f2b(hv4[rp*2] + hv4[rp*2+1]);
        hbe_w[(size_t)p * 256 + colc] = f2b(hv4[rp*2]);
        cp_w [(size_t)p * 256 + colc] =
            (unsigned int)f2b(cv4[rp*2]) | ((unsigned int)f2b(cv4[rp*2+1]) << 16);
      }
    }
  }
}

extern "C" void kernel_launch(void* const* d_in, const int* in_sizes, int n_in,
                              void* d_out, int out_size, void* d_ws, size_t ws_size,
                              hipStream_t stream) {
  const float* inputs = (const float*)d_in[0];
  const float* Wioux  = (const float*)d_in[1];
  const float* bioux  = (const float*)d_in[2];
  const float* Wiouh  = (const float*)d_in[3];
  const float* Wfx    = (const float*)d_in[4];
  const float* bfx    = (const float*)d_in[5];
  const float* Wfh    = (const float*)d_in[6];
  const float* fb     = (const float*)d_in[7];

  const int N = in_sizes[0] / 256;       // 262143
  int depth = 0;
  while (((1 << depth) - 1) < N) ++depth;  // 18

  float* out   = (float*)d_out;
  float* h_all = out + 512;

  static bool attr_done = false;
  if (!attr_done) {
    hipFuncSetAttribute((const void*)level_k<0>,
                        hipFuncAttributeMaxDynamicSharedMemorySize, 8 * 16384);
    hipFuncSetAttribute((const void*)level_k<1>,
                        hipFuncAttributeMaxDynamicSharedMemorySize, 3 * 16384);
    attr_done = true;
  }

  // ws carve: S0 (even parent levels, 65536 rows), S1 (odd, 32768 rows), xb, wb
  char* p = (char*)d_ws;
  unsigned short* hs0  = (unsigned short*)p; p += (size_t)65536 * 256 * 2;
  unsigned short* hbe0 = (unsigned short*)p; p += (size_t)65536 * 256 * 2;
  unsigned int*   cp0  = (unsigned int*)p;   p += (size_t)65536 * 256 * 4;
  unsigned short* hs1  = (unsigned short*)p; p += (size_t)32768 * 256 * 2;
  unsigned short* hbe1 = (unsigned short*)p; p += (size_t)32768 * 256 * 2;
  unsigned int*   cp1  = (unsigned int*)p;   p += (size_t)32768 * 256 * 4;
  unsigned short* xb   = (unsigned short*)p; p += (size_t)N * 256 * 2;
  unsigned short* wb   = (unsigned short*)p;

  pack_w<<<2048, 256, 0, stream>>>(Wioux, Wiouh, Wfx, Wfh, wb);
  {
    const int n8 = (N * 256) / 8;
    conv_x<<<(n8 + 255) / 256, 256, 0, stream>>>(inputs, xb, n8);
  }

  for (int d = depth - 1; d >= 0; --d) {
    const int L = 1 << d;
    const int s = L - 1;
    const int T64 = (L + 63) / 64;
    // read set = parity of this level; write set = parity of parent level
    const int rp_ = d & 1, wp_ = (d - 1) & 1;
    const unsigned short* hs_r  = rp_ ? hs1 : hs0;
    const unsigned short* hbe_r = rp_ ? hbe1 : hbe0;
    const unsigned int*   cp_r  = rp_ ? cp1 : cp0;
    unsigned short* hs_w  = wp_ ? hs1 : hs0;
    unsigned short* hbe_w = wp_ ? hbe1 : hbe0;
    unsigned int*   cp_w  = wp_ ? cp1 : cp0;
    if (d == depth - 1) {
      level_k<1><<<256, 512, 3 * 16384, stream>>>(
          xb, wb, bioux, bfx, fb, h_all,
          hs_r, hbe_r, cp_r, hs_w, hbe_w, cp_w, out, s, L, T64, 0);
    } else {
      level_k<0><<<256, 512, 8 * 16384, stream>>>(
          xb, wb, bioux, bfx, fb, h_all,
          hs_r, hbe_r, cp_r, hs_w, hbe_w, cp_w, out, s, L, T64, (d == 0) ? 1 : 0);
    }
  }
}

// Round 13
// 802.643 us; speedup vs baseline: 1.8625x; 1.8625x over previous
//
#include <hip/hip_runtime.h>

// ---------------------------------------------------------------------------
// Child-Sum TreeLSTM, complete binary tree, level-wise bottom-up, bf16 MFMA.
// Round 13 = R12 math with occupancy + register fixes:
//  - 16 col-groups (16 cols each): interior weight LDS = 64 KB -> 2 blocks/CU
//  - amdgpu_waves_per_eu(3,4): explicit register budget (no more
//    launch_bounds guessing; (512,2) rounds ran only 2 waves/SIMD = 23% occ)
//  - ONE merged K-sweep per tile: 6 acc planes (24 regs) live, each A-frag
//    (x, h-even, hsum) loaded exactly once, unroll 2 -> ~6 loads in flight,
//    peak live ~95 VGPR
//  - child epilogue writes hsum / h-even / packed-c (parent-local, coalesced);
//    f2 = sigm(xf + hsum@Wfh - h1@Wfh)  [h2@W = hs@W - h1@W]
//  - 16 cg-blocks per stripe share an XCD (bid%8=stripe%8) -> L2 A-row reuse
//
// mfma_f32_16x16x32_bf16: A lane: row=l&15, k=(l>>4)*8+e  (16B/lane)
//                         B lane: col=l&15, k=(l>>4)*8+e = W[col][k]
//                         D: col=l&15, row=(l>>4)*4+r, r=0..3
// ---------------------------------------------------------------------------

typedef __attribute__((ext_vector_type(8))) short bf16x8;
typedef __attribute__((ext_vector_type(8))) unsigned short us8;
typedef __attribute__((ext_vector_type(4))) float f32x4;
typedef __attribute__((ext_vector_type(4))) float f4;

#define MFMA16(A, B, C) __builtin_amdgcn_mfma_f32_16x16x32_bf16(A, B, C, 0, 0, 0)

__device__ __forceinline__ unsigned short f2b(float f) {
  unsigned int u = __builtin_bit_cast(unsigned int, f);
  u = u + 0x7FFFu + ((u >> 16) & 1u);   // RNE
  return (unsigned short)(u >> 16);
}
__device__ __forceinline__ float bf2f(unsigned short u) {
  unsigned int v = (unsigned int)u << 16;
  return __builtin_bit_cast(float, v);
}
__device__ __forceinline__ us8 pack8(f4 a, f4 b) {
  us8 r;
  r[0] = f2b(a[0]); r[1] = f2b(a[1]); r[2] = f2b(a[2]); r[3] = f2b(a[3]);
  r[4] = f2b(b[0]); r[5] = f2b(b[1]); r[6] = f2b(b[2]); r[7] = f2b(b[3]);
  return r;
}
__device__ __forceinline__ float sigm(float x) { return 1.0f / (1.0f + __expf(-x)); }
__device__ __forceinline__ float tanh_f(float x) { return 2.0f / (1.0f + __expf(-2.0f * x)) - 1.0f; }

__global__ void pack_w(const float* __restrict__ a,  // Wioux 768x256
                       const float* __restrict__ b,  // Wiouh 768x256
                       const float* __restrict__ c,  // Wfx   256x256
                       const float* __restrict__ d,  // Wfh   256x256
                       unsigned short* __restrict__ out) {
  int i = blockIdx.x * blockDim.x + threadIdx.x;  // 0 .. 524287
  const int A = 768 * 256;
  const int B = A + 768 * 256;
  const int C = B + 256 * 256;
  float v;
  if (i < A)      v = a[i];
  else if (i < B) v = b[i - A];
  else if (i < C) v = c[i - B];
  else            v = d[i - C];
  out[i] = f2b(v);
}

// convert ALL node x rows to bf16 (8 elems/thread)
__global__ void conv_x(const float* __restrict__ x, unsigned short* __restrict__ xb, int n8) {
  int i = blockIdx.x * blockDim.x + threadIdx.x;
  if (i >= n8) return;
  f4 a = __builtin_nontemporal_load((const f4*)(x + (size_t)i * 8));
  f4 b = __builtin_nontemporal_load((const f4*)(x + (size_t)i * 8 + 4));
  __builtin_nontemporal_store(pack8(a, b), (us8*)(xb + (size_t)i * 8));
}

// LDS planes: 0 Wx_i, 1 Wx_o, 2 Wx_u, 3 Wh_i, 4 Wh_o, 5 Wh_u, 6 Wfx, 7 Wfh
// per plane: [kc8][kg4][col16][e8] -> a wave's b128 read is 1KB contiguous.
template<int LEAF>
__global__ __launch_bounds__(512) __attribute__((amdgpu_waves_per_eu(3, 4)))
void level_k(
    const unsigned short* __restrict__ xb,     // [N][256] bf16
    const unsigned short* __restrict__ wb,     // packed bf16 weights
    const float* __restrict__ bioux,
    const float* __restrict__ bfx,
    const float* __restrict__ fb,
    float* __restrict__ h_all,                 // d_out + 512
    const unsigned short* __restrict__ hs_r,   // hsum of children, this-level-local
    const unsigned short* __restrict__ hbe_r,  // h of even child
    const unsigned int* __restrict__ cp_r,     // packed (c_even | c_odd<<16)
    unsigned short* __restrict__ hs_w,         // for parent level
    unsigned short* __restrict__ hbe_w,
    unsigned int* __restrict__ cp_w,
    float* __restrict__ out0,
    int s, int L, int T16, int root)
{
  extern __shared__ unsigned short W[];

  const int tid    = threadIdx.x;
  const int cg     = blockIdx.x >> 5;    // 0..15 column group (16 cols)
  const int stripe = blockIdx.x & 31;    // XCD = stripe % 8

  // ---- stage weights for this cg into LDS (once) ----
  const int NP = LEAF ? 3 : 8;
  #pragma unroll 1
  for (int c = tid; c < NP * 512; c += 512) {
    const int p   = c >> 9;
    const int q   = c & 511;
    const int kc  = q >> 6;
    const int kg  = (q >> 4) & 3;
    const int col = q & 15;
    const int po = (p < 3) ? p * 65536
                 : (p < 6) ? 196608 + (p - 3) * 65536
                 : (p == 6) ? 393216 : 458752;
    us8 v = *(const us8*)(wb + po + (size_t)(cg * 16 + col) * 256 + kc * 32 + kg * 8);
    *(us8*)(W + p * 4096 + ((kc * 4 + kg) * 16 + col) * 8) = v;
  }
  __syncthreads();   // only barrier; waves free-run after

  const int lane = tid & 63;
  const int wv   = tid >> 6;          // 0..7
  const int lm   = lane & 15;
  const int kgl  = lane >> 4;         // 0..3
  const int colc = cg * 16 + lm;

  const unsigned short* LW = W + kgl * 128 + lm * 8;  // + p*4096 + kc*512

  const float bi_ = bioux[colc];
  const float bo_ = bioux[256 + colc];
  const float bu_ = bioux[512 + colc];
  const float bf_ = LEAF ? 0.f : (bfx[colc] + fb[colc]);

  const int Tper = (T16 + 31) >> 5;
  const int t0   = stripe * Tper;
  const int tE   = (t0 + Tper < T16) ? (t0 + Tper) : T16;

  for (int t = t0 + wv; t < tE; t += 8) {
    const int tb16  = t * 16;
    const int drow0 = tb16 + kgl * 4;
    const unsigned short* xr = xb + (size_t)(s + tb16 + lm) * 256 + kgl * 8;
    const f32x4 z4 = {0.f, 0.f, 0.f, 0.f};

    if (!LEAF) {
      const unsigned short* hbr = hbe_r + (size_t)(tb16 + lm) * 256 + kgl * 8;
      const unsigned short* hsr = hs_r  + (size_t)(tb16 + lm) * 256 + kgl * 8;

      unsigned int cpv[4];
      #pragma unroll
      for (int r = 0; r < 4; ++r)
        cpv[r] = cp_r[(size_t)(drow0 + r) * 256 + colc];

      // ---- merged K-sweep: all 6 acc planes, each A-frag loaded once ----
      f32x4 xf = z4, f1h = z4, ai = z4, ao = z4, au = z4, fs = z4;
      #pragma unroll 2
      for (int kc = 0; kc < 8; ++kc) {
        bf16x8 ax = *(const bf16x8*)(xr  + kc * 32);
        bf16x8 a1 = *(const bf16x8*)(hbr + kc * 32);
        bf16x8 ah = *(const bf16x8*)(hsr + kc * 32);
        bf16x8 b6 = *(const bf16x8*)(LW + 6 * 4096 + kc * 512);
        bf16x8 b0 = *(const bf16x8*)(LW + 0 * 4096 + kc * 512);
        bf16x8 b1 = *(const bf16x8*)(LW + 1 * 4096 + kc * 512);
        bf16x8 b2 = *(const bf16x8*)(LW + 2 * 4096 + kc * 512);
        bf16x8 b7 = *(const bf16x8*)(LW + 7 * 4096 + kc * 512);
        bf16x8 b3 = *(const bf16x8*)(LW + 3 * 4096 + kc * 512);
        bf16x8 b4 = *(const bf16x8*)(LW + 4 * 4096 + kc * 512);
        bf16x8 b5 = *(const bf16x8*)(LW + 5 * 4096 + kc * 512);
        xf  = MFMA16(ax, b6, xf);
        ai  = MFMA16(ax, b0, ai);
        ao  = MFMA16(ax, b1, ao);
        au  = MFMA16(ax, b2, au);
        f1h = MFMA16(a1, b7, f1h);
        ai  = MFMA16(ah, b3, ai);
        ao  = MFMA16(ah, b4, ao);
        au  = MFMA16(ah, b5, au);
        fs  = MFMA16(ah, b7, fs);
      }

      // ---- epilogue ----
      float hv4[4], cv4[4];
      #pragma unroll
      for (int r = 0; r < 4; ++r) {
        const float i_ = sigm(ai[r] + bi_);
        const float u_ = tanh_f(au[r] + bu_);
        const float o_ = sigm(ao[r] + bo_);
        const float f1 = sigm(xf[r] + f1h[r] + bf_);
        const float f2 = sigm(xf[r] + fs[r] - f1h[r] + bf_);
        const float c1 = bf2f((unsigned short)(cpv[r] & 0xffffu));
        const float c2 = bf2f((unsigned short)(cpv[r] >> 16));
        const float c_ = i_ * u_ + f1 * c1 + f2 * c2;
        const float h_ = o_ * tanh_f(c_);
        cv4[r] = c_; hv4[r] = h_;
        const int j = drow0 + r;
        if (j < L)
          __builtin_nontemporal_store(h_, h_all + (size_t)(s + j) * 256 + colc);
      }
      if (root) {
        if (drow0 == 0) { out0[colc] = hv4[0]; out0[256 + colc] = cv4[0]; }
      } else {
        #pragma unroll
        for (int rp = 0; rp < 2; ++rp) {
          const int j0 = drow0 + rp * 2;
          if (j0 + 1 < L) {
            const int pp = j0 >> 1;
            hs_w [(size_t)pp * 256 + colc] = f2b(hv4[rp*2] + hv4[rp*2+1]);
            hbe_w[(size_t)pp * 256 + colc] = f2b(hv4[rp*2]);
            cp_w [(size_t)pp * 256 + colc] =
                (unsigned int)f2b(cv4[rp*2]) | ((unsigned int)f2b(cv4[rp*2+1]) << 16);
          }
        }
      }
    } else {
      // ---- leaf: i,o,u from x only ----
      f32x4 ai = z4, ao = z4, au = z4;
      #pragma unroll 4
      for (int kc = 0; kc < 8; ++kc) {
        bf16x8 ax = *(const bf16x8*)(xr + kc * 32);
        bf16x8 b0 = *(const bf16x8*)(LW + 0 * 4096 + kc * 512);
        bf16x8 b1 = *(const bf16x8*)(LW + 1 * 4096 + kc * 512);
        bf16x8 b2 = *(const bf16x8*)(LW + 2 * 4096 + kc * 512);
        ai = MFMA16(ax, b0, ai);
        ao = MFMA16(ax, b1, ao);
        au = MFMA16(ax, b2, au);
      }
      float hv4[4], cv4[4];
      #pragma unroll
      for (int r = 0; r < 4; ++r) {
        const float i_ = sigm(ai[r] + bi_);
        const float u_ = tanh_f(au[r] + bu_);
        const float o_ = sigm(ao[r] + bo_);
        const float c_ = i_ * u_;
        const float h_ = o_ * tanh_f(c_);
        cv4[r] = c_; hv4[r] = h_;
        __builtin_nontemporal_store(h_, h_all + (size_t)(s + drow0 + r) * 256 + colc);
      }
      #pragma unroll
      for (int rp = 0; rp < 2; ++rp) {
        const int pp = (drow0 + rp * 2) >> 1;
        hs_w [(size_t)pp * 256 + colc] = f2b(hv4[rp*2] + hv4[rp*2+1]);
        hbe_w[(size_t)pp * 256 + colc] = f2b(hv4[rp*2]);
        cp_w [(size_t)pp * 256 + colc] =
            (unsigned int)f2b(cv4[rp*2]) | ((unsigned int)f2b(cv4[rp*2+1]) << 16);
      }
    }
  }
}

extern "C" void kernel_launch(void* const* d_in, const int* in_sizes, int n_in,
                              void* d_out, int out_size, void* d_ws, size_t ws_size,
                              hipStream_t stream) {
  const float* inputs = (const float*)d_in[0];
  const float* Wioux  = (const float*)d_in[1];
  const float* bioux  = (const float*)d_in[2];
  const float* Wiouh  = (const float*)d_in[3];
  const float* Wfx    = (const float*)d_in[4];
  const float* bfx    = (const float*)d_in[5];
  const float* Wfh    = (const float*)d_in[6];
  const float* fb     = (const float*)d_in[7];

  const int N = in_sizes[0] / 256;       // 262143
  int depth = 0;
  while (((1 << depth) - 1) < N) ++depth;  // 18

  float* out   = (float*)d_out;
  float* h_all = out + 512;

  static bool attr_done = false;
  if (!attr_done) {
    hipFuncSetAttribute((const void*)level_k<0>,
                        hipFuncAttributeMaxDynamicSharedMemorySize, 8 * 8192);
    hipFuncSetAttribute((const void*)level_k<1>,
                        hipFuncAttributeMaxDynamicSharedMemorySize, 3 * 8192);
    attr_done = true;
  }

  // ws carve: parity-0 buffers (parents of odd levels, up to 65536 rows),
  // parity-1 (up to 32768 rows), xb (all nodes), wb
  char* p = (char*)d_ws;
  unsigned short* hs0  = (unsigned short*)p; p += (size_t)65536 * 256 * 2;
  unsigned short* hbe0 = (unsigned short*)p; p += (size_t)65536 * 256 * 2;
  unsigned int*   cp0  = (unsigned int*)p;   p += (size_t)65536 * 256 * 4;
  unsigned short* hs1  = (unsigned short*)p; p += (size_t)32768 * 256 * 2;
  unsigned short* hbe1 = (unsigned short*)p; p += (size_t)32768 * 256 * 2;
  unsigned int*   cp1  = (unsigned int*)p;   p += (size_t)32768 * 256 * 4;
  unsigned short* xb   = (unsigned short*)p; p += (size_t)N * 256 * 2;
  unsigned short* wb   = (unsigned short*)p;

  pack_w<<<2048, 256, 0, stream>>>(Wioux, Wiouh, Wfx, Wfh, wb);
  {
    const int n8 = (N * 256) / 8;
    conv_x<<<(n8 + 255) / 256, 256, 0, stream>>>(inputs, xb, n8);
  }

  for (int d = depth - 1; d >= 0; --d) {
    const int L = 1 << d;
    const int s = L - 1;
    const int T16 = (L + 15) / 16;
    const int rp_ = d & 1, wp_ = (d - 1) & 1;
    const unsigned short* hs_r  = rp_ ? hs1 : hs0;
    const unsigned short* hbe_r = rp_ ? hbe1 : hbe0;
    const unsigned int*   cp_r  = rp_ ? cp1 : cp0;
    unsigned short* hs_w  = wp_ ? hs1 : hs0;
    unsigned short* hbe_w = wp_ ? hbe1 : hbe0;
    unsigned int*   cp_w  = wp_ ? cp1 : cp0;
    if (d == depth - 1) {
      level_k<1><<<512, 512, 3 * 8192, stream>>>(
          xb, wb, bioux, bfx, fb, h_all,
          hs_r, hbe_r, cp_r, hs_w, hbe_w, cp_w, out, s, L, T16, 0);
    } else {
      level_k<0><<<512, 512, 8 * 8192, stream>>>(
          xb, wb, bioux, bfx, fb, h_all,
          hs_r, hbe_r, cp_r, hs_w, hbe_w, cp_w, out, s, L, T16, (d == 0) ? 1 : 0);
    }
  }
}